// Round 2
// baseline (227.007 us; speedup 1.0000x reference)
//
#include <hip/hip_runtime.h>
#include <hip/hip_bf16.h>
#include <stdint.h>

// Problem constants
#define B_   1024
#define L_   50
#define D_   128
#define NV_  8
#define NH_  16
#define KFC  1824   // NV*D + NH*L

typedef __bf16 bf16x8 __attribute__((ext_vector_type(8)));
typedef float  f32x4  __attribute__((ext_vector_type(4)));

static __device__ __forceinline__ bf16x8 as_bf16x8(uint4 u) {
  return __builtin_bit_cast(bf16x8, u);
}

// round-to-nearest-even f32 -> bf16 bits
static __device__ __forceinline__ unsigned short f2b(float x) {
  unsigned u = __float_as_uint(x);
  unsigned r = (u + 0x7FFFu + ((u >> 16) & 1u)) >> 16;
  return (unsigned short)r;
}

// ---- workspace layout (bytes) ----
// [0, OV)            : o buffer, B x 1824 f32  (o_v | o_h), memset 0 each launch
// [EOFF, EOFF+ESZ)   : E bf16, [b][ks(4)][row(50)][32 bf16]  (compact, 12800 B/b)
// [WOFF, WOFF+WSZ)   : hconv_w bf16, layout [i][n][j][d]
#define OV_BYTES  ((size_t)B_ * KFC * 4)                  //  7,471,104
#define EOFF      (OV_BYTES)
#define ESZ       ((size_t)B_ * 4 * 50 * 64)              // 13,107,200
#define WOFF      (EOFF + ESZ)
#define WSZ       ((size_t)L_ * NH_ * L_ * D_ * 2)        // 10,240,000
#define NEED_FULL (WOFF + WSZ)                            // 30,818,304

// ======================= kernel P: P_u copy -> out[:, 128:256]
__global__ void ck_kP(const int* __restrict__ uids, const float* __restrict__ uemb,
                      float* __restrict__ out) {
  int b = blockIdx.x, d = threadIdx.x;  // 128 threads
  out[(size_t)b * 256 + 128 + d] = uemb[(size_t)uids[b] * D_ + d];
}

// degenerate fallback: zero the z half (only used if ws_size too small)
__global__ void ck_kZ(float* __restrict__ out) {
  int i = blockIdx.x * 256 + threadIdx.x;  // 131072 exact
  int b = i >> 7, d = i & 127;
  out[(size_t)b * 256 + d] = 0.f;
}

// ======================= kernel A: gather E -> bf16 (ks-major quarters, 50 rows)
__global__ void ck_kA(const int* __restrict__ item_seq, const float* __restrict__ item_emb,
                      char* __restrict__ ws) {
  int b = blockIdx.x, tid = threadIdx.x;
  __shared__ int sidx[L_];
  if (tid < L_) sidx[tid] = item_seq[b * L_ + tid];
  __syncthreads();
  char* eg = ws + EOFF + (size_t)b * 12800;
  #pragma unroll
  for (int it = 0; it < 4; ++it) {
    int c = it * 256 + tid;
    int ks = c >> 8, row = (c >> 2) & 63, g = c & 3;
    if (row < L_) {
      const float* src = item_emb + (size_t)sidx[row] * D_ + ks * 32 + g * 8;
      float4 f0 = *(const float4*)(src);
      float4 f1 = *(const float4*)(src + 4);
      uint4 val;
      val.x = f2b(f0.x) | ((unsigned)f2b(f0.y) << 16);
      val.y = f2b(f0.z) | ((unsigned)f2b(f0.w) << 16);
      val.z = f2b(f1.x) | ((unsigned)f2b(f1.y) << 16);
      val.w = f2b(f1.z) | ((unsigned)f2b(f1.w) << 16);
      *(uint4*)(eg + ks * 3200 + row * 64 + g * 16) = val;
    }
  }
}

// ======================= kernel W: hconv_w f32 -> bf16   (5,120,000 elements exact)
__global__ void ck_kW(const float* __restrict__ hw, char* __restrict__ ws) {
  size_t idx = ((size_t)blockIdx.x * 256 + threadIdx.x) * 4;  // 5000*256*4 = 5,120,000
  float4 f = *(const float4*)(hw + idx);
  uint2 h;
  h.x = f2b(f.x) | ((unsigned)f2b(f.y) << 16);
  h.y = f2b(f.z) | ((unsigned)f2b(f.w) << 16);
  *(uint2*)(ws + WOFF + idx * 2) = h;
}

// ======================= kernel B: o_v[b,v,d] = sum_l E[b,l,d]*vf[l,v]  (f32)
__global__ void ck_kB(const int* __restrict__ item_seq, const float* __restrict__ item_emb,
                      const float* __restrict__ vf, char* __restrict__ ws) {
  int b = blockIdx.x, tid = threadIdx.x;
  __shared__ float E[L_][D_];
  __shared__ float VF[L_][NV_];
  __shared__ int sidx[L_];
  if (tid < L_) sidx[tid] = item_seq[b * L_ + tid];
  for (int c = tid; c < L_ * NV_; c += 256) VF[c / NV_][c % NV_] = vf[c];
  __syncthreads();
  for (int c = tid; c < 1600; c += 256) {  // 50 rows x 32 chunks of 4 f32
    int l = c >> 5, ch = c & 31;
    *(float4*)&E[l][ch * 4] = *(const float4*)(item_emb + (size_t)sidx[l] * D_ + ch * 4);
  }
  __syncthreads();
  int d = tid & 127, half = tid >> 7;
  float acc[4] = {0.f, 0.f, 0.f, 0.f};
  for (int l = 0; l < L_; ++l) {
    float e = E[l][d];
    #pragma unroll
    for (int vv = 0; vv < 4; ++vv) acc[vv] += e * VF[l][half * 4 + vv];
  }
  float* o = (float*)ws + (size_t)b * KFC;
  #pragma unroll
  for (int vv = 0; vv < 4; ++vv) o[(half * 4 + vv) * D_ + d] = acc[vv];
}

// ======================= kernel C: horizontal convs via bf16 MFMA
// block: 4 waves x 4 b's/wave = 16 b's; i-group of 4 (blockIdx.y), t-chunk of 16 (blockIdx.z)
// LDS: E quarter [16 b][64 rows][64B] = 64KB  +  W chunk [4 i][4 j][16 n][64B] = 16KB
__launch_bounds__(256, 2)
__global__ void ck_kC(const float* __restrict__ hconv_b, char* __restrict__ ws) {
  __shared__ char lds[81920];
  int g = 12 - (int)blockIdx.y;        // heavy groups dispatched first
  int i0 = g * 4;
  int ntmax = 50 - i0;                 // largest t-range in group
  int t0 = (int)blockIdx.z * 16;
  if (t0 >= ntmax) return;
  int hmax = min(i0 + 4, 50);
  int b0 = (int)blockIdx.x * 16;
  int tid = threadIdx.x;
  int w = tid >> 6, lane = tid & 63, r = lane & 15, gq = lane >> 4;

  const char* EG = ws + EOFF;
  const char* WG = ws + WOFF;

  f32x4 acc[4][4];
  #pragma unroll
  for (int gi = 0; gi < 4; ++gi)
    #pragma unroll
    for (int v = 0; v < 4; ++v) {
      acc[gi][v][0] = 0.f; acc[gi][v][1] = 0.f; acc[gi][v][2] = 0.f; acc[gi][v][3] = 0.f;
    }

  int bbase = 65536 + r * 64 + ((gq ^ (r & 3)) << 4);  // B-frag base (W lds)
  int abase = w * 16384;                               // this wave's 4-b E region

  int srow = tid >> 2, sgg = tid & 3;  // staging roles
  int rowg = t0 + srow;

  for (int ks = 0; ks < 4; ++ks) {
    __syncthreads();
    // ---- stage E d-quarter for 16 b's (swizzled; rows >= 50 zero) ----
    const char* ebase = EG + (size_t)b0 * 12800 + ks * 3200 + rowg * 64 + sgg * 16;
    #pragma unroll
    for (int bi = 0; bi < 16; ++bi) {
      uint4 val = make_uint4(0, 0, 0, 0);
      if (rowg < L_) val = *(const uint4*)(ebase + bi * 12800);
      *(uint4*)(lds + bi * 4096 + srow * 64 + ((sgg ^ (srow & 3)) << 4)) = val;
    }

    // W prefetch: chunk = 4 i's x 4 j's x [16 n][32 d] bf16
    uint4 wreg[4];
    auto loadW = [&](int jc) {
      int jl = (tid >> 6) & 3;
      int n = (tid >> 2) & 15;
      int gg = tid & 3;
      int j = jc + jl;
      #pragma unroll
      for (int it = 0; it < 4; ++it) {
        int i = i0 + it;
        uint4 v4 = make_uint4(0, 0, 0, 0);
        if (i < 50 && j <= i)
          v4 = *(const uint4*)(WG + 2 * ((((size_t)(i * 16 + n) * 50 + j) << 7) + ks * 32 + gg * 8));
        wreg[it] = v4;
      }
    };
    loadW(0);

    for (int jc = 0; jc < hmax; jc += 4) {
      __syncthreads();
      {  // write W chunk to LDS (swizzled on n)
        int jl = (tid >> 6) & 3;
        int n = (tid >> 2) & 15;
        int gg = tid & 3;
        #pragma unroll
        for (int it = 0; it < 4; ++it)
          *(uint4*)(lds + 65536 + ((it * 4 + jl) * 16 + n) * 64 + ((gg ^ (n & 3)) << 4)) = wreg[it];
      }
      __syncthreads();
      if (jc + 4 < hmax) loadW(jc + 4);  // prefetch next chunk under compute

      #pragma unroll
      for (int jj = 0; jj < 4; ++jj) {
        int j = jc + jj;
        int lr = r + j; lr = lr > 63 ? 63 : lr;   // clamp; clamped rows are zero rows
        int aoff = lr * 64 + ((gq ^ (lr & 3)) << 4);
        bf16x8 a[4], bf[4];
        #pragma unroll
        for (int v = 0; v < 4; ++v)
          a[v] = as_bf16x8(*(const uint4*)(lds + abase + v * 4096 + aoff));
        #pragma unroll
        for (int gi = 0; gi < 4; ++gi)
          bf[gi] = as_bf16x8(*(const uint4*)(lds + bbase + (gi * 4 + jj) * 1024));
        #pragma unroll
        for (int gi = 0; gi < 4; ++gi)
          #pragma unroll
          for (int v = 0; v < 4; ++v)
            acc[gi][v] = __builtin_amdgcn_mfma_f32_16x16x32_bf16(a[v], bf[gi], acc[gi][v], 0, 0, 0);
      }
    }
  }

  // ---- epilogue: bias + relu + masked max over t, reduce rows, atomicMax ----
  float* o = (float*)ws;
  #pragma unroll
  for (int gi = 0; gi < 4; ++gi) {
    int i = i0 + gi;
    if (i < 50) {
      int nti = 50 - i;
      float bias = hconv_b[i * 16 + r];  // col n = lane&15
      #pragma unroll
      for (int v = 0; v < 4; ++v) {
        float m = 0.f;
        #pragma unroll
        for (int e = 0; e < 4; ++e) {
          int t = t0 + gq * 4 + e;       // C/D row = (lane>>4)*4 + e
          float val = acc[gi][v][e] + bias;
          val = fmaxf(val, 0.f);
          if (t < nti) m = fmaxf(m, val);
        }
        m = fmaxf(m, __shfl_xor(m, 16));
        m = fmaxf(m, __shfl_xor(m, 32));
        if (lane < 16) {
          int b = b0 + w * 4 + v;
          atomicMax((unsigned int*)&o[(size_t)b * KFC + 1024 + i * 16 + r], __float_as_uint(m));
        }
      }
    }
  }
}

// ======================= kernel D: FC (full K in one pass) + bias + relu -> out[:, :128]
// grid (16, 8): 64-row M-tile x 16-col N-tile; 4 waves each own 16 rows.
__launch_bounds__(256)
__global__ void ck_kD(const float* __restrict__ fc_w, const float* __restrict__ fc_b,
                      const char* __restrict__ ws, float* __restrict__ out) {
  __shared__ char ldsD[5120];  // A [64 rows][64B] @0 ; B [16 n][64B] @4096
  int b0 = blockIdx.x * 64, n0 = blockIdx.y * 16;
  int tid = threadIdx.x, w = tid >> 6, lane = tid & 63, r = lane & 15, gq = lane >> 4;
  const float* o = (const float*)ws;

  f32x4 acc; acc[0] = 0.f; acc[1] = 0.f; acc[2] = 0.f; acc[3] = 0.f;

  int rl = tid >> 2, ch = tid & 3;           // A staging: row, granule-of-8-f32
  const float* asrc = o + (size_t)(b0 + rl) * KFC + ch * 8;
  int kk = tid >> 3, nn = tid & 7;           // B staging: k-row, n (and n+8)

  float4 fa0 = *(const float4*)(asrc);
  float4 fa1 = *(const float4*)(asrc + 4);
  float fb0 = fc_w[(size_t)kk * D_ + n0 + nn];
  float fb1 = fc_w[(size_t)kk * D_ + n0 + nn + 8];

  int arow_off = rl * 64 + ((ch ^ (rl & 3)) << 4);
  int rloc = w * 16 + r;
  int ard = rloc * 64 + ((gq ^ (rloc & 3)) << 4);
  int brd = 4096 + r * 64 + ((gq ^ (r & 3)) << 4);

  for (int s = 0; s < 57; ++s) {
    __syncthreads();
    {
      uint4 v;
      v.x = f2b(fa0.x) | ((unsigned)f2b(fa0.y) << 16);
      v.y = f2b(fa0.z) | ((unsigned)f2b(fa0.w) << 16);
      v.z = f2b(fa1.x) | ((unsigned)f2b(fa1.y) << 16);
      v.w = f2b(fa1.z) | ((unsigned)f2b(fa1.w) << 16);
      *(uint4*)(ldsD + arow_off) = v;
      *(unsigned short*)(ldsD + 4096 + nn * 64 + (((kk >> 3) ^ (nn & 3)) << 4) + (kk & 7) * 2) = f2b(fb0);
      *(unsigned short*)(ldsD + 4096 + (nn + 8) * 64 + (((kk >> 3) ^ ((nn + 8) & 3)) << 4) + (kk & 7) * 2) = f2b(fb1);
    }
    __syncthreads();
    if (s + 1 < 57) {  // prefetch next K-slice under this slice's MFMA
      int kb = (s + 1) * 32;
      fa0 = *(const float4*)(asrc + kb);
      fa1 = *(const float4*)(asrc + kb + 4);
      fb0 = fc_w[(size_t)(kb + kk) * D_ + n0 + nn];
      fb1 = fc_w[(size_t)(kb + kk) * D_ + n0 + nn + 8];
    }
    bf16x8 a   = as_bf16x8(*(const uint4*)(ldsD + ard));
    bf16x8 bfr = as_bf16x8(*(const uint4*)(ldsD + brd));
    acc = __builtin_amdgcn_mfma_f32_16x16x32_bf16(a, bfr, acc, 0, 0, 0);
  }

  float bias = fc_b[n0 + r];
  #pragma unroll
  for (int e = 0; e < 4; ++e) {
    int row = b0 + w * 16 + gq * 4 + e;
    out[(size_t)row * 256 + n0 + r] = fmaxf(acc[e] + bias, 0.f);
  }
}

extern "C" void kernel_launch(void* const* d_in, const int* in_sizes, int n_in,
                              void* d_out, int out_size, void* d_ws, size_t ws_size,
                              hipStream_t stream) {
  const int*   user_ids = (const int*)d_in[0];
  const int*   item_seq = (const int*)d_in[1];
  const float* user_emb = (const float*)d_in[2];
  const float* item_emb = (const float*)d_in[3];
  const float* vfilter  = (const float*)d_in[4];
  const float* hconv_w  = (const float*)d_in[5];
  const float* hconv_b  = (const float*)d_in[6];
  const float* fc_w     = (const float*)d_in[7];
  const float* fc_b     = (const float*)d_in[8];
  float* out = (float*)d_out;
  char*  ws  = (char*)d_ws;

  ck_kP<<<dim3(B_), dim3(128), 0, stream>>>(user_ids, user_emb, out);

  if (ws_size < NEED_FULL) {
    // workspace too small — degenerate diagnostic path (z = 0), no ws touched
    ck_kZ<<<dim3(512), dim3(256), 0, stream>>>(out);
    return;
  }

  // o buffer must be zero each call (atomicMax accumulation semantics)
  hipMemsetAsync(ws, 0, OV_BYTES, stream);

  ck_kA<<<dim3(B_), dim3(256), 0, stream>>>(item_seq, item_emb, ws);
  ck_kW<<<dim3(5000), dim3(256), 0, stream>>>(hconv_w, ws);
  ck_kB<<<dim3(B_), dim3(256), 0, stream>>>(item_seq, item_emb, vfilter, ws);
  ck_kC<<<dim3(64, 13, 4), dim3(256), 0, stream>>>(hconv_b, ws);
  ck_kD<<<dim3(16, 8), dim3(256), 0, stream>>>(fc_w, fc_b, ws, out);
}